// Round 11
// baseline (116.156 us; speedup 1.0000x reference)
//
#include <hip/hip_runtime.h>

// NCA update via fp16 MFMA — two-phase LDS design (no shuffles).
// Phase 1 (thread = pixel): coalesced loads of 16ch x 3 rows, build packed
//   fp16x2 column-sums + mids + ch3 colmax + update gate in LDS.
// Phase 2 (wave = 4 MFMA tiles): Y fragment from 4x ds_read_b128 per tile
//   (mid + 3 neighbor colsums), GEMM1(12 mfma)+relu+GEMM2(6 mfma), blend
//   from LDS mids, store.
// R11 fix: store column is start + pxl (R10 dropped the 64*wid wave offset ->
// columns 64..255 of each half-row never written).

#define HH 512
#define WW 512
#define CC 16
#define HID 192
#define HW (HH * WW)

typedef _Float16 half8  __attribute__((ext_vector_type(8)));
typedef _Float16 half2v __attribute__((ext_vector_type(2)));
typedef __fp16   fp16x2 __attribute__((ext_vector_type(2)));
typedef float    f32x4  __attribute__((ext_vector_type(4)));
typedef unsigned int u32;
typedef u32 u32x4 __attribute__((ext_vector_type(4)));

__device__ __forceinline__ u32 pkrtz(float a, float b) {
    return __builtin_bit_cast(u32, __builtin_amdgcn_cvt_pkrtz(a, b));
}
__device__ __forceinline__ half2v i2h(u32 v) { return __builtin_bit_cast(half2v, v); }
__device__ __forceinline__ u32 h2i(half2v v) { return __builtin_bit_cast(u32, v); }

__global__ __launch_bounds__(256, 2) void nca_kernel(
    const float* __restrict__ x,
    const float* __restrict__ noise,
    const float* __restrict__ w1w,
    const float* __restrict__ w1b,
    const float* __restrict__ w2w,
    float* __restrict__ out)
{
    __shared__ u32   cs_s[258][12];   // packed fp16x2 colsums (cols start-1 .. start+256)
    __shared__ u32   mid_s[256][12];  // packed fp16x2 center-row x
    __shared__ float cm_s[258];       // ch3 column max
    __shared__ float um_s[256];       // update gate floor(noise+0.5)
    __shared__ __align__(16) float bl_s[HID];

    const int tid  = threadIdx.x;
    const int lane = tid & 63;
    const int wid  = tid >> 6;
    const int p    = lane & 15;   // pixel-in-tile
    const int gq   = lane >> 4;   // fragment k-group

    // XCD swizzle: 4096 blocks -> 8 chunks of 512 consecutive half-rows
    const int bid = blockIdx.x;
    const int lin = (bid & 7) * 512 + (bid >> 3);
    const int b     = lin >> 10;
    const int rem   = lin & 1023;
    const int i     = rem >> 1;             // image row
    const int start = (rem & 1) * 256;      // half-row base column

    if (tid < HID) bl_s[tid] = w1b[tid];

    // resident W1 A-fragments: lane holds W1[o=16t+p][c=8*gq+e]
    half8 w1f[12];
    #pragma unroll
    for (int t = 0; t < 12; ++t) {
        const float* src = w1w + (16 * t + p) * 32 + 8 * gq;
        #pragma unroll
        for (int e = 0; e < 8; ++e) w1f[t][e] = (_Float16)src[e];
    }
    // resident W2 A-fragments (identity rows, sigma slot map as verified in R3)
    half8 w2f[6];
    #pragma unroll
    for (int f = 0; f < 6; ++f) {
        const float* s0 = w2w + p * HID + 32 * f + 4 * gq;
        #pragma unroll
        for (int e = 0; e < 4; ++e) {
            w2f[f][e]     = (_Float16)s0[e];
            w2f[f][4 + e] = (_Float16)s0[16 + e];
        }
    }

    const int im = (i == 0) ? HH - 1 : i - 1;
    const int ip = (i == HH - 1) ? 0 : i + 1;
    const float* xb = x + (size_t)b * CC * HW;
    const float* pT = xb + im * WW;
    const float* pM = xb + (size_t)i * WW;
    const float* pB = xb + ip * WW;
    const float* nrow = noise + (size_t)b * HW + (size_t)i * WW;
    float* orow = out + (size_t)b * CC * HW + (size_t)i * WW;

    // ---- phase 1: perception staging (thread = pixel start+tid) ----
    {
        const int colg = start + tid;
        #pragma unroll 1
        for (int k = 0; k < 4; ++k) {            // 4 channels per round
            float tr[4], mr[4], br[4];
            #pragma unroll
            for (int cc = 0; cc < 4; ++cc) {
                const size_t o = (size_t)(4 * k + cc) * HW + colg;
                tr[cc] = pT[o]; mr[cc] = pM[o]; br[cc] = pB[o];
            }
            float cs[4];
            #pragma unroll
            for (int cc = 0; cc < 4; ++cc) cs[cc] = tr[cc] + mr[cc] + br[cc];
            cs_s[tid + 1][2 * k]     = pkrtz(cs[0], cs[1]);
            cs_s[tid + 1][2 * k + 1] = pkrtz(cs[2], cs[3]);
            mid_s[tid][2 * k]        = pkrtz(mr[0], mr[1]);
            mid_s[tid][2 * k + 1]    = pkrtz(mr[2], mr[3]);
            if (k == 0) cm_s[tid + 1] = fmaxf(fmaxf(tr[3], mr[3]), br[3]);
        }
        um_s[tid] = floorf(nrow[colg] + 0.5f);

        // halo columns (block edges, circular in-row wrap)
        if (tid == 0 || tid == 255) {
            const int hc   = (tid == 0) ? ((start + WW - 1) & (WW - 1))
                                        : ((start + 256) & (WW - 1));
            const int hidx = (tid == 0) ? 0 : 257;
            float hcm = 0.f;
            #pragma unroll 1
            for (int k = 0; k < 4; ++k) {
                float tr[4], mr[4], br[4];
                #pragma unroll
                for (int cc = 0; cc < 4; ++cc) {
                    const size_t o = (size_t)(4 * k + cc) * HW + hc;
                    tr[cc] = pT[o]; mr[cc] = pM[o]; br[cc] = pB[o];
                }
                float cs[4];
                #pragma unroll
                for (int cc = 0; cc < 4; ++cc) cs[cc] = tr[cc] + mr[cc] + br[cc];
                cs_s[hidx][2 * k]     = pkrtz(cs[0], cs[1]);
                cs_s[hidx][2 * k + 1] = pkrtz(cs[2], cs[3]);
                if (k == 0) hcm = fmaxf(fmaxf(tr[3], mr[3]), br[3]);
            }
            cm_s[hidx] = hcm;
        }
    }
    __syncthreads();

    // ---- phase 2: MFMA tiles (wave wid owns px 64*wid .. 64*wid+63) ----
    const f32x4* blv = (const f32x4*)bl_s;
    const half2v k9 = {(_Float16)9.0f, (_Float16)9.0f};
    const bool isCenter = (gq < 2);
    const int woff = 4 * (gq & 1);

    #pragma unroll 2
    for (int tt = 0; tt < 4; ++tt) {
        const int pxl = 64 * wid + 16 * tt + p;   // local pixel index

        // Y fragment: mid + 3 neighbor colsums, packed fp16 math
        const u32x4 midv = *(const u32x4*)&mid_s[pxl][woff];
        const u32x4 csm  = *(const u32x4*)&cs_s[pxl][woff];       // col-1
        const u32x4 cs0  = *(const u32x4*)&cs_s[pxl + 1][woff];   // col
        const u32x4 csp  = *(const u32x4*)&cs_s[pxl + 2][woff];   // col+1
        union { half8 v; u32 iw[4]; } yf;
        #pragma unroll
        for (int w = 0; w < 4; ++w) {
            const half2v s9  = i2h(csm[w]) + i2h(cs0[w]) + i2h(csp[w]);
            const half2v lap = k9 * i2h(midv[w]) - s9;
            yf.iw[w] = isCenter ? midv[w] : h2i(lap);
        }

        const float alive =
            (fmaxf(fmaxf(cm_s[pxl], cm_s[pxl + 1]), cm_s[pxl + 2]) > 0.1f) ? 1.0f : 0.0f;
        const float um = um_s[pxl];

        // GEMM1 + relu + GEMM2 (H stays lane-local)
        f32x4 acc2a = {0.f, 0.f, 0.f, 0.f}, acc2b = {0.f, 0.f, 0.f, 0.f};
        #pragma unroll
        for (int f = 0; f < 6; ++f) {
            const f32x4 ba = blv[8 * f + gq];
            const f32x4 bb = blv[8 * f + 4 + gq];
            const f32x4 a1 = __builtin_amdgcn_mfma_f32_16x16x32_f16(w1f[2 * f],     yf.v, ba, 0, 0, 0);
            const f32x4 a2 = __builtin_amdgcn_mfma_f32_16x16x32_f16(w1f[2 * f + 1], yf.v, bb, 0, 0, 0);
            union { half8 v; fp16x2 f2[4]; } hf;
            hf.f2[0] = __builtin_amdgcn_cvt_pkrtz(fmaxf(a1[0], 0.f), fmaxf(a1[1], 0.f));
            hf.f2[1] = __builtin_amdgcn_cvt_pkrtz(fmaxf(a1[2], 0.f), fmaxf(a1[3], 0.f));
            hf.f2[2] = __builtin_amdgcn_cvt_pkrtz(fmaxf(a2[0], 0.f), fmaxf(a2[1], 0.f));
            hf.f2[3] = __builtin_amdgcn_cvt_pkrtz(fmaxf(a2[2], 0.f), fmaxf(a2[3], 0.f));
            if (f & 1) acc2b = __builtin_amdgcn_mfma_f32_16x16x32_f16(w2f[f], hf.v, acc2b, 0, 0, 0);
            else       acc2a = __builtin_amdgcn_mfma_f32_16x16x32_f16(w2f[f], hf.v, acc2a, 0, 0, 0);
        }

        // blend + store: lane stores channels 4*gq..4*gq+3 at pixel pxl
        const half2v xa = i2h(mid_s[pxl][2 * gq]);
        const half2v xc = i2h(mid_s[pxl][2 * gq + 1]);
        const float xr[4] = {(float)xa[0], (float)xa[1], (float)xc[0], (float)xc[1]};
        const int col = start + pxl;              // R11 fix (was start+16*tt+p)
        #pragma unroll
        for (int r = 0; r < 4; ++r) {
            const float dx = acc2a[r] + acc2b[r];
            orow[(size_t)(4 * gq + r) * HW + col] = (xr[r] + dx * um) * alive;
        }
    }
}

extern "C" void kernel_launch(void* const* d_in, const int* in_sizes, int n_in,
                              void* d_out, int out_size, void* d_ws, size_t ws_size,
                              hipStream_t stream)
{
    const float* x     = (const float*)d_in[0];
    const float* noise = (const float*)d_in[1];
    const float* w1w   = (const float*)d_in[2];
    const float* w1b   = (const float*)d_in[3];
    const float* w2w   = (const float*)d_in[4];
    float* out = (float*)d_out;

    nca_kernel<<<4096, 256, 0, stream>>>(x, noise, w1w, w1b, w2w, out);
}

// Round 13
// 59.066 us; speedup vs baseline: 1.9666x; 1.9666x over previous
//
#include <hip/hip_runtime.h>

// NCA update via fp16 MFMA, half-row-per-wave, software-pipelined (R9 base).
// R12/R13: neighbor exchange via DPP row shifts (update_dpp old = seam
// broadcast from ds_swizzle), ReLU as v_pk_max_f16 after pkrtz.
// R13 fix: DPP directions were swapped in R12 — row_shr:1 = lane i <- i-1
// (left neighbor, invalid p=0 keeps old=left seam); row_shl:1 = lane i <- i+1
// (right neighbor, invalid p=15 keeps old=right seam).
// NOTE: __launch_bounds__(256,4) clamps VGPR to 64 -> spills, 4x slower. Keep (256,2).

#define HH 512
#define WW 512
#define CC 16
#define HID 192
#define NT 16          // tiles per wave (half row: 256 px)
#define HW (HH * WW)

typedef _Float16 half8  __attribute__((ext_vector_type(8)));
typedef _Float16 half2v __attribute__((ext_vector_type(2)));
typedef __fp16   fp16x2 __attribute__((ext_vector_type(2)));
typedef float    f32x4  __attribute__((ext_vector_type(4)));
typedef unsigned int u32;

__device__ __forceinline__ u32 h2i(half2v v) { return __builtin_bit_cast(u32, v); }
__device__ __forceinline__ half2v i2h(u32 v) { return __builtin_bit_cast(half2v, v); }
__device__ __forceinline__ u32 pkrtz(float a, float b) {
    return __builtin_bit_cast(u32, __builtin_amdgcn_cvt_pkrtz(a, b));
}
__device__ __forceinline__ u32 fi(float f) { return __builtin_bit_cast(u32, f); }
__device__ __forceinline__ float if_(u32 v) { return __builtin_bit_cast(float, v); }

// ds_swizzle patterns (BitMode): src_lane = ((lane & and) | or) ^ xor
#define SWZ_P15 0x1F0   // (lane&0x10)|0xF : p=15 of own 16-group
#define SWZ_P0  0x0010  // (lane&0x10)    : p=0  of own 16-group
#define SWZ_LO  0x000F  // lane&0xF       : same p in low group of 32-half

#define SWZ(v, patt) ((u32)__builtin_amdgcn_ds_swizzle((int)(v), (patt)))
// DPP row shifts (16-lane rows); invalid lanes keep `old` (bound_ctrl=false).
// UP1: lane i <- lane i-1 (row_shr:1), invalid lane p=0   -> old (left seam)
// DN1: lane i <- lane i+1 (row_shl:1), invalid lane p=15  -> old (right seam)
#define DPP_UP1(old, src) ((u32)__builtin_amdgcn_update_dpp((int)(old), (int)(src), 0x111, 0xF, 0xF, false))
#define DPP_DN1(old, src) ((u32)__builtin_amdgcn_update_dpp((int)(old), (int)(src), 0x101, 0xF, 0xF, false))

__global__ __launch_bounds__(256, 2) void nca_mfma_kernel(
    const float* __restrict__ x,
    const float* __restrict__ noise,
    const float* __restrict__ w1w,
    const float* __restrict__ w1b,
    const float* __restrict__ w2w,
    float* __restrict__ out)
{
    __shared__ __align__(16) float bl[HID];
    const int tid  = threadIdx.x;
    const int lane = tid & 63;
    const int wid  = tid >> 6;
    const int p    = lane & 15;   // pixel-in-tile / matrix row-col index
    const int gq   = lane >> 4;   // fragment k-group

    // XCD-aware swizzle: 1024 blocks -> 8 chunks of 128 consecutive blocks
    const int bid = blockIdx.x;
    const int lin = (bid & 7) * 128 + (bid >> 3);
    // wave-uniform scalars, forced into SGPRs
    const int gr    = __builtin_amdgcn_readfirstlane(lin * 4 + wid); // half-row id
    const int b     = gr >> 10;
    const int rem   = gr & 1023;
    const int i     = rem >> 1;             // image row
    const int start = (rem & 1) * (WW / 2); // which half

    // stage bias to LDS
    for (int k = tid; k < HID; k += 256) bl[k] = w1b[k];
    __syncthreads();

    // resident W1 A-fragments: lane holds W1[o=16t+p][c=8*gq+e]
    half8 w1f[12];
    #pragma unroll
    for (int t = 0; t < 12; ++t) {
        const float* src = w1w + (16 * t + p) * 32 + 8 * gq;
        #pragma unroll
        for (int e = 0; e < 8; ++e) w1f[t][e] = (_Float16)src[e];
    }
    // resident W2 A-fragments, rows permuted by pi(p)=swap bits2,3:
    // D-row m then holds W2-row pi(m), so gq group stores channels it staged.
    const int pi_p = (p & 3) | ((p & 4) << 1) | ((p & 8) >> 1);
    half8 w2f[6];
    #pragma unroll
    for (int f = 0; f < 6; ++f) {
        const float* s0 = w2w + pi_p * HID + 32 * f + 4 * gq;
        #pragma unroll
        for (int e = 0; e < 4; ++e) {
            w2f[f][e]     = (_Float16)s0[e];
            w2f[f][4 + e] = (_Float16)s0[16 + e];
        }
    }

    const int im = (i == 0) ? HH - 1 : i - 1;
    const int ip = (i == HH - 1) ? 0 : i + 1;
    const int rT = im * WW, rM = i * WW, rB = ip * WW;
    // uniform row-base pointers (SGPR pairs); per-lane part is col only
    const float* xbch = x + ((size_t)b * CC + 8 * (gq & 1)) * HW;
    const float* pT = xbch + rT;
    const float* pM = xbch + rM;
    const float* pB = xbch + rB;
    const float* nrow = noise + (size_t)b * HW + rM;
    float* orow = out + (size_t)b * CC * HW + rM;

    const bool hiSel = (gq >= 2);             // blend mids from e=4..7?
    const int gqsw = ((gq & 1) << 1) | (gq >> 1);  // store channel group

    // raw loads: 8 channels x 3 rows at column `col` (uniform base + col)
    auto loadRaw = [&](int col, float r[24]) {
        #pragma unroll
        for (int e = 0; e < 8; ++e) {
            r[3 * e + 0] = pT[e * HW + col];
            r[3 * e + 1] = pM[e * HW + col];
            r[3 * e + 2] = pB[e * HW + col];
        }
    };
    // combine raws -> packed colsums, packed mids, f32 blend mids, ch3 col-max
    auto combine = [&](const float r[24], half2v pcs[4], half2v pm[4],
                       float mx[4], float& cm) {
        #pragma unroll
        for (int w = 0; w < 4; ++w) {
            const float cs0 = r[6 * w + 0] + r[6 * w + 1] + r[6 * w + 2];
            const float cs1 = r[6 * w + 3] + r[6 * w + 4] + r[6 * w + 5];
            pcs[w] = i2h(pkrtz(cs0, cs1));
            pm[w]  = i2h(pkrtz(r[6 * w + 1], r[6 * w + 4]));
        }
        #pragma unroll
        for (int j = 0; j < 4; ++j)
            mx[j] = hiSel ? r[3 * (j + 4) + 1] : r[3 * j + 1];
        cm = fmaxf(fmaxf(r[9], r[10]), r[11]);   // e==3 rows (ch3 for gq 0/2)
    };

    half2v pcsA[4], pcsB[4], pcsC[4], pmB[4], pmC[4];
    float  mxB[4], mxC[4];
    float  cmA, cmB, cmC;
    float  nzB, nzC;
    float  rr[24];

    // prologue: uniform-column halo (all lanes hold colsum of col start-1)
    {
        float rh[24]; half2v dum[4]; float dmx[4];
        loadRaw((start - 1) & (WW - 1), rh);
        combine(rh, pcsA, dum, dmx, cmA);
        float r0[24];
        loadRaw(start + p, r0);
        combine(r0, pcsB, pmB, mxB, cmB);
        float r1[24];
        loadRaw(start + 16 + p, r1);
        combine(r1, pcsC, pmC, mxC, cmC);
        nzB = nrow[start + p];
        nzC = nrow[start + 16 + p];
    }

    const f32x4* blv = (const f32x4*)bl;
    const half2v k9 = {(_Float16)9.0f, (_Float16)9.0f};
    const bool isCenter = (gq < 2);
    const u32 PZ = 0;   // packed fp16 zero for v_pk_max_f16

    #pragma unroll 4
    for (int t = 0; t < NT; ++t) {
        // (1) issue raw + noise loads for tile t+2 (masked col; tail iters junk-but-valid)
        const int colP = (start + 16 * (t + 2) + p) & (WW - 1);
        loadRaw(colP, rr);
        const float nzD = nrow[colP];

        // (2) compute tile t ------------------------------------------------
        union { half8 v; u32 iw[4]; } yf;
        #pragma unroll
        for (int w = 0; w < 4; ++w) {
            const u32 bw = h2i(pcsB[w]);
            const u32 pl = SWZ(h2i(pcsA[w]), SWZ_P15);   // left seam value (col 16t-1)
            const u32 pr = SWZ(h2i(pcsC[w]), SWZ_P0);    // right seam value (col 16t+16)
            const u32 lft = DPP_UP1(pl, bw);             // cs[p-1], p=0  -> pl
            const u32 rgt = DPP_DN1(pr, bw);             // cs[p+1], p=15 -> pr
            const half2v s9  = i2h(lft) + i2h(bw) + i2h(rgt);
            const half2v lap = k9 * pmB[w] - s9;
            yf.iw[w] = isCenter ? h2i(pmB[w]) : h2i(lap);
        }

        // alive mask (3x3 circular max of channel 3; valid in gq 0/2, broadcast)
        const u32 pml = SWZ(fi(cmA), SWZ_P15);
        const u32 pmr = SWZ(fi(cmC), SWZ_P0);
        const float ml = if_(DPP_UP1(pml, fi(cmB)));
        const float mr = if_(DPP_DN1(pmr, fi(cmB)));
        const float rmax  = fmaxf(fmaxf(ml, cmB), mr);
        const float av    = if_(SWZ(fi(rmax), SWZ_LO));
        const float alive = (av > 0.1f) ? 1.0f : 0.0f;
        const float um    = floorf(nzB + 0.5f);

        // GEMM1 + relu + GEMM2 (H stays lane-local)
        f32x4 acc2a = {0.f, 0.f, 0.f, 0.f}, acc2b = {0.f, 0.f, 0.f, 0.f};
        #pragma unroll
        for (int f = 0; f < 6; ++f) {
            const f32x4 ba = blv[8 * f + gq];
            const f32x4 bb = blv[8 * f + 4 + gq];
            const f32x4 a1 = __builtin_amdgcn_mfma_f32_16x16x32_f16(w1f[2 * f],     yf.v, ba, 0, 0, 0);
            const f32x4 a2 = __builtin_amdgcn_mfma_f32_16x16x32_f16(w1f[2 * f + 1], yf.v, bb, 0, 0, 0);
            union { half8 v; u32 iw[4]; } hf;
            #pragma unroll
            for (int w = 0; w < 4; ++w) {
                const f32x4& aa = (w < 2) ? a1 : a2;
                const u32 pk = pkrtz(aa[2 * (w & 1)], aa[2 * (w & 1) + 1]);
                u32 rl;
                asm("v_pk_max_f16 %0, %1, %2" : "=v"(rl) : "v"(pk), "v"(PZ));
                hf.iw[w] = rl;
            }
            if (f & 1) acc2b = __builtin_amdgcn_mfma_f32_16x16x32_f16(w2f[f], hf.v, acc2b, 0, 0, 0);
            else       acc2a = __builtin_amdgcn_mfma_f32_16x16x32_f16(w2f[f], hf.v, acc2a, 0, 0, 0);
        }

        // blend + store: lane stores channel 4*gqsw + r at its own column,
        // x comes from the staged f32 mids (no global re-read).
        const int col = start + 16 * t + p;
        #pragma unroll
        for (int r = 0; r < 4; ++r) {
            const float dx = acc2a[r] + acc2b[r];
            orow[(size_t)(4 * gqsw + r) * HW + col] = (mxB[r] + dx * um) * alive;
        }

        // (3) combine tile t+2 raws, rotate pipeline ------------------------
        half2v pcsD[4], pmD[4]; float mxD[4]; float cmD;
        combine(rr, pcsD, pmD, mxD, cmD);
        #pragma unroll
        for (int w = 0; w < 4; ++w) {
            pcsA[w] = pcsB[w];
            pcsB[w] = pcsC[w]; pmB[w] = pmC[w];
            pcsC[w] = pcsD[w]; pmC[w] = pmD[w];
        }
        #pragma unroll
        for (int j = 0; j < 4; ++j) { mxB[j] = mxC[j]; mxC[j] = mxD[j]; }
        cmA = cmB; cmB = cmC; cmC = cmD;
        nzB = nzC; nzC = nzD;
    }
}

extern "C" void kernel_launch(void* const* d_in, const int* in_sizes, int n_in,
                              void* d_out, int out_size, void* d_ws, size_t ws_size,
                              hipStream_t stream)
{
    const float* x     = (const float*)d_in[0];
    const float* noise = (const float*)d_in[1];
    const float* w1w   = (const float*)d_in[2];
    const float* w1b   = (const float*)d_in[3];
    const float* w2w   = (const float*)d_in[4];
    float* out = (float*)d_out;

    nca_mfma_kernel<<<1024, 256, 0, stream>>>(x, noise, w1w, w1b, w2w, out);
}